// Round 3
// baseline (922.504 us; speedup 1.0000x reference)
//
#include <hip/hip_runtime.h>
#include <math.h>

// Problem constants (B=1)
#define S_LEN   4096
#define D_MODEL 768
#define N_HEAD  12
#define H_DIM   64
#define NELEM   (S_LEN * D_MODEL)    // 3,145,728
#define WELEM   (D_MODEL * D_MODEL)  // 589,824

typedef unsigned short ushort;
typedef __attribute__((ext_vector_type(8))) short short8;
typedef __attribute__((ext_vector_type(4))) float f32x4;

__device__ __forceinline__ ushort f2bh(float f) {
  unsigned u = __float_as_uint(f);
  u += 0x7fffu + ((u >> 16) & 1u);  // round-to-nearest-even
  return (ushort)(u >> 16);
}
__device__ __forceinline__ float bh2f(ushort h) {
  return __uint_as_float(((unsigned)h) << 16);
}

// XOR swizzle for 64-bf16 (128B) LDS rows: spreads 16B slots across banks.
#define SWZ(row, colByte) ((((row) * 128) + (colByte)) ^ (((row) & 7) << 4))

// ============================================================================
// convert_x: fp32 -> bf16 hi/lo planes (element-wise, 4/thread)
// ============================================================================
__global__ __launch_bounds__(256)
void convert_x(const float* __restrict__ x, ushort* __restrict__ xh,
               ushort* __restrict__ xl) {
  size_t i = ((size_t)blockIdx.x * 256 + threadIdx.x) * 4;
  float4 v = *reinterpret_cast<const float4*>(&x[i]);
  ushort4 hv, lv;
  hv.x = f2bh(v.x); lv.x = f2bh(v.x - bh2f(hv.x));
  hv.y = f2bh(v.y); lv.y = f2bh(v.y - bh2f(hv.y));
  hv.z = f2bh(v.z); lv.z = f2bh(v.z - bh2f(hv.z));
  hv.w = f2bh(v.w); lv.w = f2bh(v.w - bh2f(hv.w));
  *reinterpret_cast<ushort4*>(&xh[i]) = hv;
  *reinterpret_cast<ushort4*>(&xl[i]) = lv;
}

// convert_w: 4 weight matrices -> hi/lo planes (plane z: 0=q,1=k,2=v,3=o)
__global__ __launch_bounds__(256)
void convert_w(const float* __restrict__ wq, const float* __restrict__ wk,
               const float* __restrict__ wv, const float* __restrict__ wo,
               ushort* __restrict__ WH, ushort* __restrict__ WL) {
  int z = blockIdx.z;
  const float* src = (z == 0) ? wq : (z == 1) ? wk : (z == 2) ? wv : wo;
  ushort* oh = WH + (size_t)z * WELEM;
  ushort* ol = WL + (size_t)z * WELEM;
  size_t i = ((size_t)blockIdx.x * 256 + threadIdx.x) * 4;
  float4 v = *reinterpret_cast<const float4*>(&src[i]);
  ushort4 hv, lv;
  hv.x = f2bh(v.x); lv.x = f2bh(v.x - bh2f(hv.x));
  hv.y = f2bh(v.y); lv.y = f2bh(v.y - bh2f(hv.y));
  hv.z = f2bh(v.z); lv.z = f2bh(v.z - bh2f(hv.z));
  hv.w = f2bh(v.w); lv.w = f2bh(v.w - bh2f(hv.w));
  *reinterpret_cast<ushort4*>(&oh[i]) = hv;
  *reinterpret_cast<ushort4*>(&ol[i]) = lv;
}

// ============================================================================
// bf16x3 MFMA GEMM core: C[128x64] += A(hi+lo) * W(hi+lo)^T
// A row-major [M][768] bf16 planes, W row-major [N][768] bf16 planes.
// 256 thr = 4 waves (2x2); wave = 64x32 sub-tile = 4x2 16x16 frags.
// BK=64, swizzled LDS, reg-staged with early-issue prefetch (T14).
// ============================================================================
__device__ __forceinline__ void gemm_bf3_core(
    const ushort* __restrict__ Ah, const ushort* __restrict__ Al,
    const ushort* __restrict__ Wh, const ushort* __restrict__ Wl,
    int rowbase, int colbase, f32x4 (&acc)[4][2]) {
  __shared__ __align__(16) ushort AhS[128 * 64];
  __shared__ __align__(16) ushort AlS[128 * 64];
  __shared__ __align__(16) ushort WhS[64 * 64];
  __shared__ __align__(16) ushort WlS[64 * 64];
  char* AhB = (char*)AhS; char* AlB = (char*)AlS;
  char* WhB = (char*)WhS; char* WlB = (char*)WlS;

  const int tid  = threadIdx.x;
  const int lane = tid & 63;
  const int w    = tid >> 6;
  const int wm   = w >> 1;   // 0..1 -> rows wm*64
  const int wn   = w & 1;    // 0..1 -> cols wn*32
  const int lr   = lane & 15;
  const int lk   = lane >> 4;

#pragma unroll
  for (int mt = 0; mt < 4; ++mt)
#pragma unroll
    for (int nt = 0; nt < 2; ++nt) acc[mt][nt] = {0.f, 0.f, 0.f, 0.f};

  float4 ga[8], gw[4];
  auto issue = [&](int k0) {
#pragma unroll
    for (int p = 0; p < 4; ++p) {
      int id = tid + p * 256;
      int r  = id >> 3;
      int ce = (id & 7) * 8;
      size_t off = (size_t)(rowbase + r) * D_MODEL + k0 + ce;
      ga[p]     = *reinterpret_cast<const float4*>(Ah + off);
      ga[4 + p] = *reinterpret_cast<const float4*>(Al + off);
    }
#pragma unroll
    for (int p = 0; p < 2; ++p) {
      int id = tid + p * 256;
      int r  = id >> 3;
      int ce = (id & 7) * 8;
      size_t off = (size_t)(colbase + r) * D_MODEL + k0 + ce;
      gw[p]     = *reinterpret_cast<const float4*>(Wh + off);
      gw[2 + p] = *reinterpret_cast<const float4*>(Wl + off);
    }
  };

  issue(0);
  for (int ks = 0; ks < D_MODEL / 64; ++ks) {
    __syncthreads();  // prior compute done reading LDS
#pragma unroll
    for (int p = 0; p < 4; ++p) {
      int id = tid + p * 256;
      int r  = id >> 3;
      int cb = (id & 7) * 16;
      *reinterpret_cast<float4*>(AhB + SWZ(r, cb)) = ga[p];
      *reinterpret_cast<float4*>(AlB + SWZ(r, cb)) = ga[4 + p];
    }
#pragma unroll
    for (int p = 0; p < 2; ++p) {
      int id = tid + p * 256;
      int r  = id >> 3;
      int cb = (id & 7) * 16;
      *reinterpret_cast<float4*>(WhB + SWZ(r, cb)) = gw[p];
      *reinterpret_cast<float4*>(WlB + SWZ(r, cb)) = gw[2 + p];
    }
    __syncthreads();
    if (ks < D_MODEL / 64 - 1) issue((ks + 1) * 64);  // overlap with compute

#pragma unroll
    for (int kc = 0; kc < 2; ++kc) {
      short8 ah[4], al[4], bh[2], bl[2];
#pragma unroll
      for (int mt = 0; mt < 4; ++mt) {
        int o = SWZ(wm * 64 + mt * 16 + lr, kc * 64 + lk * 16);
        ah[mt] = *reinterpret_cast<const short8*>(AhB + o);
        al[mt] = *reinterpret_cast<const short8*>(AlB + o);
      }
#pragma unroll
      for (int nt = 0; nt < 2; ++nt) {
        int o = SWZ(wn * 32 + nt * 16 + lr, kc * 64 + lk * 16);
        bh[nt] = *reinterpret_cast<const short8*>(WhB + o);
        bl[nt] = *reinterpret_cast<const short8*>(WlB + o);
      }
#pragma unroll
      for (int mt = 0; mt < 4; ++mt)
#pragma unroll
        for (int nt = 0; nt < 2; ++nt) {
          acc[mt][nt] = __builtin_amdgcn_mfma_f32_16x16x32_bf16(
              ah[mt], bh[nt], acc[mt][nt], 0, 0, 0);
          acc[mt][nt] = __builtin_amdgcn_mfma_f32_16x16x32_bf16(
              al[mt], bh[nt], acc[mt][nt], 0, 0, 0);
          acc[mt][nt] = __builtin_amdgcn_mfma_f32_16x16x32_bf16(
              ah[mt], bl[nt], acc[mt][nt], 0, 0, 0);
        }
    }
  }
}

// QKV projections: grid (12, 32, 3); z: 0=Q(scale 1/8), 1=K, 2=V.
// Output: hi/lo bf16 planes, layout [Qh][Ql][Kh][Kl][Vrh][Vrl] off QKV base.
__global__ __launch_bounds__(256)
void gemm_qkv_bf3(const ushort* __restrict__ xh, const ushort* __restrict__ xl,
                  const ushort* __restrict__ WH, const ushort* __restrict__ WL,
                  ushort* __restrict__ QKV) {
  const int z = blockIdx.z;
  const ushort* Wh = WH + (size_t)z * WELEM;
  const ushort* Wl = WL + (size_t)z * WELEM;
  ushort* oh = QKV + (size_t)z * (2 * NELEM);
  ushort* ol = oh + NELEM;
  const float scale = (z == 0) ? 0.125f : 1.0f;
  const int rowbase = blockIdx.y * 128;
  const int colbase = blockIdx.x * 64;

  f32x4 acc[4][2];
  gemm_bf3_core(xh, xl, Wh, Wl, rowbase, colbase, acc);

  const int lane = threadIdx.x & 63, w = threadIdx.x >> 6;
  const int wm = w >> 1, wn = w & 1, lr = lane & 15, lk = lane >> 4;
#pragma unroll
  for (int mt = 0; mt < 4; ++mt)
#pragma unroll
    for (int nt = 0; nt < 2; ++nt)
#pragma unroll
      for (int j = 0; j < 4; ++j) {
        int rg = rowbase + wm * 64 + mt * 16 + lk * 4 + j;
        int cg = colbase + wn * 32 + nt * 16 + lr;
        float v = acc[mt][nt][j] * scale;
        ushort hh = f2bh(v);
        oh[(size_t)rg * D_MODEL + cg] = hh;
        ol[(size_t)rg * D_MODEL + cg] = f2bh(v - bh2f(hh));
      }
}

// Output projection: fp32 out + bias.
__global__ __launch_bounds__(256)
void gemm_out_bf3(const ushort* __restrict__ ch, const ushort* __restrict__ cl,
                  const ushort* __restrict__ woh, const ushort* __restrict__ wol,
                  const float* __restrict__ bo, float* __restrict__ out) {
  const int rowbase = blockIdx.y * 128;
  const int colbase = blockIdx.x * 64;
  f32x4 acc[4][2];
  gemm_bf3_core(ch, cl, woh, wol, rowbase, colbase, acc);

  const int lane = threadIdx.x & 63, w = threadIdx.x >> 6;
  const int wm = w >> 1, wn = w & 1, lr = lane & 15, lk = lane >> 4;
#pragma unroll
  for (int nt = 0; nt < 2; ++nt) {
    int cg = colbase + wn * 32 + nt * 16 + lr;
    float bb = bo[cg];
#pragma unroll
    for (int mt = 0; mt < 4; ++mt)
#pragma unroll
      for (int j = 0; j < 4; ++j) {
        int rg = rowbase + wm * 64 + mt * 16 + lk * 4 + j;
        out[(size_t)rg * D_MODEL + cg] = acc[mt][nt][j] + bb;
      }
  }
}

// ============================================================================
// V transpose: row-major hi/lo planes -> [h][d][s] hi/lo planes.
// ============================================================================
__global__ __launch_bounds__(256)
void convert_vt(const ushort* __restrict__ Vrh, const ushort* __restrict__ Vrl,
                ushort* __restrict__ Vth, ushort* __restrict__ Vtl) {
  __shared__ ushort th[64][68];
  __shared__ ushort tl[64][68];
  const int tid = threadIdx.x;
  const int s0  = blockIdx.x * 64;
  const int h   = blockIdx.y;
#pragma unroll
  for (int it = 0; it < 4; ++it) {
    int id = tid + it * 256;
    int s  = id >> 4;
    int c4 = (id & 15) * 4;
    size_t g = (size_t)(s0 + s) * D_MODEL + h * H_DIM + c4;
    ushort4 vh = *reinterpret_cast<const ushort4*>(&Vrh[g]);
    ushort4 vl = *reinterpret_cast<const ushort4*>(&Vrl[g]);
    th[c4 + 0][s] = vh.x; th[c4 + 1][s] = vh.y;
    th[c4 + 2][s] = vh.z; th[c4 + 3][s] = vh.w;
    tl[c4 + 0][s] = vl.x; tl[c4 + 1][s] = vl.y;
    tl[c4 + 2][s] = vl.z; tl[c4 + 3][s] = vl.w;
  }
  __syncthreads();
#pragma unroll
  for (int it = 0; it < 4; ++it) {
    int id = tid + it * 256;
    int d  = id >> 4;
    int s4 = (id & 15) * 4;
    ushort4 oh, ol;
    oh.x = th[d][s4 + 0]; oh.y = th[d][s4 + 1];
    oh.z = th[d][s4 + 2]; oh.w = th[d][s4 + 3];
    ol.x = tl[d][s4 + 0]; ol.y = tl[d][s4 + 1];
    ol.z = tl[d][s4 + 2]; ol.w = tl[d][s4 + 3];
    size_t o = (size_t)(h * H_DIM + d) * S_LEN + s0 + s4;
    *reinterpret_cast<ushort4*>(&Vth[o]) = oh;
    *reinterpret_cast<ushort4*>(&Vtl[o]) = ol;
  }
}

// ============================================================================
// Flash attention fwd (causal) via bf16x3 MFMA, fp32 online softmax.
// Block: 1 head x 64 q-rows, 4 waves x 16 rows. T14 async-stage split.
// ============================================================================
__global__ __launch_bounds__(256)
void attn_mfma(const ushort* __restrict__ Qh_g, const ushort* __restrict__ Ql_g,
               const ushort* __restrict__ Kh_g, const ushort* __restrict__ Kl_g,
               const ushort* __restrict__ Vh_g, const ushort* __restrict__ Vl_g,
               ushort* __restrict__ CTXh, ushort* __restrict__ CTXl) {
  __shared__ __align__(16) ushort Kh_s[64 * 64];
  __shared__ __align__(16) ushort Kl_s[64 * 64];
  __shared__ __align__(16) ushort Vh_s[64 * 64];
  __shared__ __align__(16) ushort Vl_s[64 * 64];
  __shared__ unsigned int P_s[4][16 * 68];  // per-wave, packed hi|lo

  char* KhB = (char*)Kh_s;
  char* KlB = (char*)Kl_s;
  char* VhB = (char*)Vh_s;
  char* VlB = (char*)Vl_s;

  const int tid  = threadIdx.x;
  const int lane = tid & 63;
  const int w    = tid >> 6;
  const int qb   = gridDim.x - 1 - blockIdx.x;  // big-work blocks first
  const int h    = blockIdx.y;
  const int lr   = lane & 15;
  const int lk   = lane >> 4;
  const float NEG = -1e30f;

  // ---- Prologue: stage Q tile through K buffers, hoist A-frags to regs ----
#pragma unroll
  for (int p = 0; p < 2; ++p) {
    int id = tid + p * 256;
    int r  = id >> 3;
    int cb = (id & 7) * 16;
    int ce = (id & 7) * 8;
    size_t g = (size_t)(qb * 64 + r) * D_MODEL + h * H_DIM + ce;
    *reinterpret_cast<float4*>(KhB + SWZ(r, cb)) =
        *reinterpret_cast<const float4*>(Qh_g + g);
    *reinterpret_cast<float4*>(KlB + SWZ(r, cb)) =
        *reinterpret_cast<const float4*>(Ql_g + g);
  }
  __syncthreads();
  short8 aqh[2], aql[2];
#pragma unroll
  for (int kc = 0; kc < 2; ++kc) {
    int ao = SWZ(w * 16 + lr, kc * 64 + lk * 16);
    aqh[kc] = *reinterpret_cast<const short8*>(KhB + ao);
    aql[kc] = *reinterpret_cast<const short8*>(KlB + ao);
  }

  f32x4 o[4];
  float m[4], l[4];
#pragma unroll
  for (int t = 0; t < 4; ++t) o[t] = {0.f, 0.f, 0.f, 0.f};
#pragma unroll
  for (int r = 0; r < 4; ++r) { m[r] = NEG; l[r] = 0.f; }

  // T14: register prefetch of K/V tiles.
  float4 gkh[2], gkl[2], gvh[2], gvl[2];
  auto issueKV = [&](int kt) {
#pragma unroll
    for (int p = 0; p < 2; ++p) {
      int id = tid + p * 256;
      int r  = id >> 3;
      int ce = (id & 7) * 8;
      size_t gk = (size_t)(kt * 64 + r) * D_MODEL + h * H_DIM + ce;
      size_t gv = (size_t)(h * H_DIM + r) * S_LEN + kt * 64 + ce;
      gkh[p] = *reinterpret_cast<const float4*>(Kh_g + gk);
      gkl[p] = *reinterpret_cast<const float4*>(Kl_g + gk);
      gvh[p] = *reinterpret_cast<const float4*>(Vh_g + gv);
      gvl[p] = *reinterpret_cast<const float4*>(Vl_g + gv);
    }
  };
  issueKV(0);

  for (int kt = 0; kt <= qb; ++kt) {
    __syncthreads();  // prior tile's LDS reads done (covers Q-frag reads too)
#pragma unroll
    for (int p = 0; p < 2; ++p) {
      int id = tid + p * 256;
      int r  = id >> 3;
      int cb = (id & 7) * 16;
      *reinterpret_cast<float4*>(KhB + SWZ(r, cb)) = gkh[p];
      *reinterpret_cast<float4*>(KlB + SWZ(r, cb)) = gkl[p];
      *reinterpret_cast<float4*>(VhB + SWZ(r, cb)) = gvh[p];
      *reinterpret_cast<float4*>(VlB + SWZ(r, cb)) = gvl[p];
    }
    __syncthreads();
    if (kt < qb) issueKV(kt + 1);  // in flight during compute

    // ---- S = Q K^T (bf16x3) ----
    f32x4 sacc[4];
#pragma unroll
    for (int t = 0; t < 4; ++t) sacc[t] = {0.f, 0.f, 0.f, 0.f};
#pragma unroll
    for (int kc = 0; kc < 2; ++kc) {
#pragma unroll
      for (int t = 0; t < 4; ++t) {
        int bo = SWZ(t * 16 + lr, kc * 64 + lk * 16);
        short8 bh = *reinterpret_cast<const short8*>(KhB + bo);
        short8 bl = *reinterpret_cast<const short8*>(KlB + bo);
        sacc[t] = __builtin_amdgcn_mfma_f32_16x16x32_bf16(aqh[kc], bh, sacc[t], 0, 0, 0);
        sacc[t] = __builtin_amdgcn_mfma_f32_16x16x32_bf16(aql[kc], bh, sacc[t], 0, 0, 0);
        sacc[t] = __builtin_amdgcn_mfma_f32_16x16x32_bf16(aqh[kc], bl, sacc[t], 0, 0, 0);
      }
    }

    // ---- causal mask on the diagonal tile ----
    if (kt == qb) {
#pragma unroll
      for (int t = 0; t < 4; ++t) {
        int colg = t * 16 + lr;
#pragma unroll
        for (int r = 0; r < 4; ++r) {
          int rowg = w * 16 + lk * 4 + r;
          if (colg > rowg) sacc[t][r] = NEG;
        }
      }
    }

    // ---- online softmax (rows live in 16-lane groups) ----
    float pf[4][4];  // [t][r]
#pragma unroll
    for (int r = 0; r < 4; ++r) {
      float mx = fmaxf(fmaxf(sacc[0][r], sacc[1][r]),
                       fmaxf(sacc[2][r], sacc[3][r]));
      mx = fmaxf(mx, __shfl_xor(mx, 1));
      mx = fmaxf(mx, __shfl_xor(mx, 2));
      mx = fmaxf(mx, __shfl_xor(mx, 4));
      mx = fmaxf(mx, __shfl_xor(mx, 8));
      float mnew  = fmaxf(m[r], mx);
      float alpha = __expf(m[r] - mnew);
      float rs = 0.f;
#pragma unroll
      for (int t = 0; t < 4; ++t) {
        float p = __expf(sacc[t][r] - mnew);
        pf[t][r] = p;
        rs += p;
      }
      rs += __shfl_xor(rs, 1);
      rs += __shfl_xor(rs, 2);
      rs += __shfl_xor(rs, 4);
      rs += __shfl_xor(rs, 8);
      l[r] = l[r] * alpha + rs;
      m[r] = mnew;
#pragma unroll
      for (int t = 0; t < 4; ++t) o[t][r] *= alpha;
    }

    // ---- P -> per-wave LDS (packed hi|lo u32) ----
    unsigned int* pw = P_s[w];
#pragma unroll
    for (int r = 0; r < 4; ++r) {
#pragma unroll
      for (int t = 0; t < 4; ++t) {
        float p = pf[t][r];
        ushort ph = f2bh(p);
        ushort pl = f2bh(p - bh2f(ph));
        pw[(lk * 4 + r) * 68 + t * 16 + lr] =
            (unsigned)ph | ((unsigned)pl << 16);
      }
    }

    // ---- O += P V (bf16x3) ----
#pragma unroll
    for (int kc = 0; kc < 2; ++kc) {
      const uint4* pp = reinterpret_cast<const uint4*>(
          &pw[lr * 68 + kc * 32 + lk * 8]);
      uint4 u0 = pp[0];
      uint4 u1 = pp[1];
      short8 pah, pal;
      pah[0] = (short)(u0.x & 0xffff); pal[0] = (short)(u0.x >> 16);
      pah[1] = (short)(u0.y & 0xffff); pal[1] = (short)(u0.y >> 16);
      pah[2] = (short)(u0.z & 0xffff); pal[2] = (short)(u0.z >> 16);
      pah[3] = (short)(u0.w & 0xffff); pal[3] = (short)(u0.w >> 16);
      pah[4] = (short)(u1.x & 0xffff); pal[4] = (short)(u1.x >> 16);
      pah[5] = (short)(u1.y & 0xffff); pal[5] = (short)(u1.y >> 16);
      pah[6] = (short)(u1.z & 0xffff); pal[6] = (short)(u1.z >> 16);
      pah[7] = (short)(u1.w & 0xffff); pal[7] = (short)(u1.w >> 16);
#pragma unroll
      for (int t = 0; t < 4; ++t) {
        int bo = SWZ(t * 16 + lr, kc * 64 + lk * 16);
        short8 vh = *reinterpret_cast<const short8*>(VhB + bo);
        short8 vl = *reinterpret_cast<const short8*>(VlB + bo);
        o[t] = __builtin_amdgcn_mfma_f32_16x16x32_bf16(pah, vh, o[t], 0, 0, 0);
        o[t] = __builtin_amdgcn_mfma_f32_16x16x32_bf16(pah, vl, o[t], 0, 0, 0);
        o[t] = __builtin_amdgcn_mfma_f32_16x16x32_bf16(pal, vh, o[t], 0, 0, 0);
      }
    }
  }

  // ---- epilogue: normalize, store ctx as hi/lo bf16 planes ----
  float inv[4];
#pragma unroll
  for (int r = 0; r < 4; ++r) inv[r] = 1.f / l[r];
#pragma unroll
  for (int t = 0; t < 4; ++t)
#pragma unroll
    for (int r = 0; r < 4; ++r) {
      size_t idx = (size_t)(qb * 64 + w * 16 + lk * 4 + r) * D_MODEL +
                   h * H_DIM + t * 16 + lr;
      float v = o[t][r] * inv[r];
      ushort hh = f2bh(v);
      CTXh[idx] = hh;
      CTXl[idx] = f2bh(v - bh2f(hh));
    }
}

// ============================================================================
extern "C" void kernel_launch(void* const* d_in, const int* in_sizes, int n_in,
                              void* d_out, int out_size, void* d_ws,
                              size_t ws_size, hipStream_t stream) {
  // setup_inputs order: x, w_k, w_q, w_v, w_o, b_o
  const float* x  = (const float*)d_in[0];
  const float* wk = (const float*)d_in[1];
  const float* wq = (const float*)d_in[2];
  const float* wv = (const float*)d_in[3];
  const float* wo = (const float*)d_in[4];
  const float* bo = (const float*)d_in[5];
  float* out = (float*)d_out;

  // Workspace layout (ushort elements):
  ushort* xh   = (ushort*)d_ws;
  ushort* xl   = xh + NELEM;
  ushort* WH   = xl + NELEM;          // 4 planes: q,k,v,o
  ushort* WL   = WH + 4 * (size_t)WELEM;
  ushort* QKV  = WL + 4 * (size_t)WELEM;  // [Qh][Ql][Kh][Kl][Vrh][Vrl]
  ushort* Qh   = QKV;
  ushort* Ql   = Qh + NELEM;
  ushort* Kh   = Ql + NELEM;
  ushort* Kl   = Kh + NELEM;
  ushort* Vrh  = Kl + NELEM;
  ushort* Vrl  = Vrh + NELEM;
  ushort* Vth  = Vrl + NELEM;
  ushort* Vtl  = Vth + NELEM;
  ushort* CTXh = Vtl + NELEM;
  ushort* CTXl = CTXh + NELEM;

  dim3 blk(256);
  convert_x<<<dim3(NELEM / 4 / 256), blk, 0, stream>>>(x, xh, xl);
  convert_w<<<dim3(WELEM / 4 / 256, 1, 4), blk, 0, stream>>>(wq, wk, wv, wo,
                                                             WH, WL);
  gemm_qkv_bf3<<<dim3(D_MODEL / 64, S_LEN / 128, 3), blk, 0, stream>>>(
      xh, xl, WH, WL, QKV);
  convert_vt<<<dim3(S_LEN / 64, N_HEAD), blk, 0, stream>>>(Vrh, Vrl, Vth, Vtl);
  attn_mfma<<<dim3(S_LEN / 64, N_HEAD), blk, 0, stream>>>(
      Qh, Ql, Kh, Kl, Vth, Vtl, CTXh, CTXl);
  gemm_out_bf3<<<dim3(D_MODEL / 64, S_LEN / 128, 1), blk, 0, stream>>>(
      CTXh, CTXl, WH + 3 * (size_t)WELEM, WL + 3 * (size_t)WELEM, bo, out);
}

// Round 4
// 423.126 us; speedup vs baseline: 2.1802x; 2.1802x over previous
//
#include <hip/hip_runtime.h>
#include <math.h>

// Problem constants (B=1)
#define S_LEN   4096
#define D_MODEL 768
#define N_HEAD  12
#define H_DIM   64
#define NELEM   (S_LEN * D_MODEL)    // 3,145,728
#define WELEM   (D_MODEL * D_MODEL)  // 589,824

typedef unsigned short ushort;
typedef __attribute__((ext_vector_type(8))) short short8;
typedef __attribute__((ext_vector_type(4))) float f32x4;

__device__ __forceinline__ ushort f2bh(float f) {
  unsigned u = __float_as_uint(f);
  u += 0x7fffu + ((u >> 16) & 1u);  // round-to-nearest-even
  return (ushort)(u >> 16);
}
__device__ __forceinline__ float bh2f(ushort h) {
  return __uint_as_float(((unsigned)h) << 16);
}

// XOR swizzle for 64-bf16 (128B) LDS rows: spreads 16B slots across banks.
#define SWZ(row, colByte) ((((row) * 128) + (colByte)) ^ (((row) & 7) << 4))

// ============================================================================
// convert_x: fp32 -> bf16 hi/lo planes (element-wise, 4/thread)
// ============================================================================
__global__ __launch_bounds__(256)
void convert_x(const float* __restrict__ x, ushort* __restrict__ xh,
               ushort* __restrict__ xl) {
  size_t i = ((size_t)blockIdx.x * 256 + threadIdx.x) * 4;
  float4 v = *reinterpret_cast<const float4*>(&x[i]);
  ushort4 hv, lv;
  hv.x = f2bh(v.x); lv.x = f2bh(v.x - bh2f(hv.x));
  hv.y = f2bh(v.y); lv.y = f2bh(v.y - bh2f(hv.y));
  hv.z = f2bh(v.z); lv.z = f2bh(v.z - bh2f(hv.z));
  hv.w = f2bh(v.w); lv.w = f2bh(v.w - bh2f(hv.w));
  *reinterpret_cast<ushort4*>(&xh[i]) = hv;
  *reinterpret_cast<ushort4*>(&xl[i]) = lv;
}

// convert_w: 4 weight matrices -> hi/lo planes (plane z: 0=q,1=k,2=v,3=o)
__global__ __launch_bounds__(256)
void convert_w(const float* __restrict__ wq, const float* __restrict__ wk,
               const float* __restrict__ wv, const float* __restrict__ wo,
               ushort* __restrict__ WH, ushort* __restrict__ WL) {
  int z = blockIdx.z;
  const float* src = (z == 0) ? wq : (z == 1) ? wk : (z == 2) ? wv : wo;
  ushort* oh = WH + (size_t)z * WELEM;
  ushort* ol = WL + (size_t)z * WELEM;
  size_t i = ((size_t)blockIdx.x * 256 + threadIdx.x) * 4;
  float4 v = *reinterpret_cast<const float4*>(&src[i]);
  ushort4 hv, lv;
  hv.x = f2bh(v.x); lv.x = f2bh(v.x - bh2f(hv.x));
  hv.y = f2bh(v.y); lv.y = f2bh(v.y - bh2f(hv.y));
  hv.z = f2bh(v.z); lv.z = f2bh(v.z - bh2f(hv.z));
  hv.w = f2bh(v.w); lv.w = f2bh(v.w - bh2f(hv.w));
  *reinterpret_cast<ushort4*>(&oh[i]) = hv;
  *reinterpret_cast<ushort4*>(&ol[i]) = lv;
}

// ============================================================================
// bf16x3 MFMA GEMM core: C[128x64] += A(hi+lo) * W(hi+lo)^T
// 256 thr = 4 waves (2x2); wave = 64x32 sub-tile = 4x2 16x16 frags.
// BK=64, swizzled LDS. T14 prefetch in NAMED registers (no arrays/lambdas --
// R3's array-in-lambda prefetch was allocated to scratch: 500MB HBM writes).
// ============================================================================
__device__ __forceinline__ void gemm_bf3_core(
    const ushort* __restrict__ Ah, const ushort* __restrict__ Al,
    const ushort* __restrict__ Wh, const ushort* __restrict__ Wl,
    int rowbase, int colbase, f32x4 (&acc)[4][2]) {
  __shared__ __align__(16) ushort AhS[128 * 64];
  __shared__ __align__(16) ushort AlS[128 * 64];
  __shared__ __align__(16) ushort WhS[64 * 64];
  __shared__ __align__(16) ushort WlS[64 * 64];
  char* AhB = (char*)AhS; char* AlB = (char*)AlS;
  char* WhB = (char*)WhS; char* WlB = (char*)WlS;

  const int tid  = threadIdx.x;
  const int lane = tid & 63;
  const int w    = tid >> 6;
  const int wm   = w >> 1;
  const int wn   = w & 1;
  const int lr   = lane & 15;
  const int lk   = lane >> 4;

  const int r0 = tid >> 3;          // 0..31
  const int cb = (tid & 7) * 16;    // byte col in LDS row
  const int ce = (tid & 7) * 8;     // element col
  const int sA0 = SWZ(r0, cb);
  const int sA1 = SWZ(r0 + 32, cb);
  const int sA2 = SWZ(r0 + 64, cb);
  const int sA3 = SWZ(r0 + 96, cb);

#pragma unroll
  for (int mt = 0; mt < 4; ++mt)
#pragma unroll
    for (int nt = 0; nt < 2; ++nt) acc[mt][nt] = {0.f, 0.f, 0.f, 0.f};

  // Named prefetch registers (A: 4 row-groups x hi/lo; W: 2 x hi/lo).
  float4 gA0h, gA1h, gA2h, gA3h, gA0l, gA1l, gA2l, gA3l;
  float4 gW0h, gW1h, gW0l, gW1l;

#define GEMM_ISSUE(k0_)                                                     \
  {                                                                         \
    size_t oA = (size_t)(rowbase + r0) * D_MODEL + (k0_) + ce;              \
    const size_t st = 32 * (size_t)D_MODEL;                                 \
    gA0h = *reinterpret_cast<const float4*>(Ah + oA);                       \
    gA1h = *reinterpret_cast<const float4*>(Ah + oA + st);                  \
    gA2h = *reinterpret_cast<const float4*>(Ah + oA + 2 * st);              \
    gA3h = *reinterpret_cast<const float4*>(Ah + oA + 3 * st);              \
    gA0l = *reinterpret_cast<const float4*>(Al + oA);                       \
    gA1l = *reinterpret_cast<const float4*>(Al + oA + st);                  \
    gA2l = *reinterpret_cast<const float4*>(Al + oA + 2 * st);              \
    gA3l = *reinterpret_cast<const float4*>(Al + oA + 3 * st);              \
    size_t oW = (size_t)(colbase + r0) * D_MODEL + (k0_) + ce;              \
    gW0h = *reinterpret_cast<const float4*>(Wh + oW);                       \
    gW1h = *reinterpret_cast<const float4*>(Wh + oW + st);                  \
    gW0l = *reinterpret_cast<const float4*>(Wl + oW);                       \
    gW1l = *reinterpret_cast<const float4*>(Wl + oW + st);                  \
  }

  GEMM_ISSUE(0);
  for (int ks = 0; ks < D_MODEL / 64; ++ks) {
    __syncthreads();  // prior compute done reading LDS
    *reinterpret_cast<float4*>(AhB + sA0) = gA0h;
    *reinterpret_cast<float4*>(AhB + sA1) = gA1h;
    *reinterpret_cast<float4*>(AhB + sA2) = gA2h;
    *reinterpret_cast<float4*>(AhB + sA3) = gA3h;
    *reinterpret_cast<float4*>(AlB + sA0) = gA0l;
    *reinterpret_cast<float4*>(AlB + sA1) = gA1l;
    *reinterpret_cast<float4*>(AlB + sA2) = gA2l;
    *reinterpret_cast<float4*>(AlB + sA3) = gA3l;
    *reinterpret_cast<float4*>(WhB + sA0) = gW0h;
    *reinterpret_cast<float4*>(WhB + sA1) = gW1h;
    *reinterpret_cast<float4*>(WlB + sA0) = gW0l;
    *reinterpret_cast<float4*>(WlB + sA1) = gW1l;
    __syncthreads();
    if (ks < D_MODEL / 64 - 1) GEMM_ISSUE((ks + 1) * 64);  // hide under MFMA

#pragma unroll
    for (int kc = 0; kc < 2; ++kc) {
      short8 ah[4], al[4], bh[2], bl[2];
#pragma unroll
      for (int mt = 0; mt < 4; ++mt) {
        int o = SWZ(wm * 64 + mt * 16 + lr, kc * 64 + lk * 16);
        ah[mt] = *reinterpret_cast<const short8*>(AhB + o);
        al[mt] = *reinterpret_cast<const short8*>(AlB + o);
      }
#pragma unroll
      for (int nt = 0; nt < 2; ++nt) {
        int o = SWZ(wn * 32 + nt * 16 + lr, kc * 64 + lk * 16);
        bh[nt] = *reinterpret_cast<const short8*>(WhB + o);
        bl[nt] = *reinterpret_cast<const short8*>(WlB + o);
      }
#pragma unroll
      for (int mt = 0; mt < 4; ++mt)
#pragma unroll
        for (int nt = 0; nt < 2; ++nt) {
          acc[mt][nt] = __builtin_amdgcn_mfma_f32_16x16x32_bf16(
              ah[mt], bh[nt], acc[mt][nt], 0, 0, 0);
          acc[mt][nt] = __builtin_amdgcn_mfma_f32_16x16x32_bf16(
              al[mt], bh[nt], acc[mt][nt], 0, 0, 0);
          acc[mt][nt] = __builtin_amdgcn_mfma_f32_16x16x32_bf16(
              ah[mt], bl[nt], acc[mt][nt], 0, 0, 0);
        }
    }
  }
#undef GEMM_ISSUE
}

// QKV projections: grid (12, 32, 3); z: 0=Q(scale 1/8), 1=K, 2=V.
__global__ __launch_bounds__(256)
void gemm_qkv_bf3(const ushort* __restrict__ xh, const ushort* __restrict__ xl,
                  const ushort* __restrict__ WH, const ushort* __restrict__ WL,
                  ushort* __restrict__ QKV) {
  const int z = blockIdx.z;
  const ushort* Wh = WH + (size_t)z * WELEM;
  const ushort* Wl = WL + (size_t)z * WELEM;
  ushort* oh = QKV + (size_t)z * (2 * NELEM);
  ushort* ol = oh + NELEM;
  const float scale = (z == 0) ? 0.125f : 1.0f;
  const int rowbase = blockIdx.y * 128;
  const int colbase = blockIdx.x * 64;

  f32x4 acc[4][2];
  gemm_bf3_core(xh, xl, Wh, Wl, rowbase, colbase, acc);

  const int lane = threadIdx.x & 63, w = threadIdx.x >> 6;
  const int wm = w >> 1, wn = w & 1, lr = lane & 15, lk = lane >> 4;
#pragma unroll
  for (int mt = 0; mt < 4; ++mt)
#pragma unroll
    for (int nt = 0; nt < 2; ++nt)
#pragma unroll
      for (int j = 0; j < 4; ++j) {
        int rg = rowbase + wm * 64 + mt * 16 + lk * 4 + j;
        int cg = colbase + wn * 32 + nt * 16 + lr;
        float v = acc[mt][nt][j] * scale;
        ushort hh = f2bh(v);
        oh[(size_t)rg * D_MODEL + cg] = hh;
        ol[(size_t)rg * D_MODEL + cg] = f2bh(v - bh2f(hh));
      }
}

// Output projection: fp32 out + bias.
__global__ __launch_bounds__(256)
void gemm_out_bf3(const ushort* __restrict__ ch, const ushort* __restrict__ cl,
                  const ushort* __restrict__ woh, const ushort* __restrict__ wol,
                  const float* __restrict__ bo, float* __restrict__ out) {
  const int rowbase = blockIdx.y * 128;
  const int colbase = blockIdx.x * 64;
  f32x4 acc[4][2];
  gemm_bf3_core(ch, cl, woh, wol, rowbase, colbase, acc);

  const int lane = threadIdx.x & 63, w = threadIdx.x >> 6;
  const int wm = w >> 1, wn = w & 1, lr = lane & 15, lk = lane >> 4;
#pragma unroll
  for (int nt = 0; nt < 2; ++nt) {
    int cg = colbase + wn * 32 + nt * 16 + lr;
    float bb = bo[cg];
#pragma unroll
    for (int mt = 0; mt < 4; ++mt)
#pragma unroll
      for (int j = 0; j < 4; ++j) {
        int rg = rowbase + wm * 64 + mt * 16 + lk * 4 + j;
        out[(size_t)rg * D_MODEL + cg] = acc[mt][nt][j] + bb;
      }
  }
}

// ============================================================================
// V transpose: row-major hi/lo planes -> [h][d][s] hi/lo planes.
// ============================================================================
__global__ __launch_bounds__(256)
void convert_vt(const ushort* __restrict__ Vrh, const ushort* __restrict__ Vrl,
                ushort* __restrict__ Vth, ushort* __restrict__ Vtl) {
  __shared__ ushort th[64][68];
  __shared__ ushort tl[64][68];
  const int tid = threadIdx.x;
  const int s0  = blockIdx.x * 64;
  const int h   = blockIdx.y;
#pragma unroll
  for (int it = 0; it < 4; ++it) {
    int id = tid + it * 256;
    int s  = id >> 4;
    int c4 = (id & 15) * 4;
    size_t g = (size_t)(s0 + s) * D_MODEL + h * H_DIM + c4;
    ushort4 vh = *reinterpret_cast<const ushort4*>(&Vrh[g]);
    ushort4 vl = *reinterpret_cast<const ushort4*>(&Vrl[g]);
    th[c4 + 0][s] = vh.x; th[c4 + 1][s] = vh.y;
    th[c4 + 2][s] = vh.z; th[c4 + 3][s] = vh.w;
    tl[c4 + 0][s] = vl.x; tl[c4 + 1][s] = vl.y;
    tl[c4 + 2][s] = vl.z; tl[c4 + 3][s] = vl.w;
  }
  __syncthreads();
#pragma unroll
  for (int it = 0; it < 4; ++it) {
    int id = tid + it * 256;
    int d  = id >> 4;
    int s4 = (id & 15) * 4;
    ushort4 oh, ol;
    oh.x = th[d][s4 + 0]; oh.y = th[d][s4 + 1];
    oh.z = th[d][s4 + 2]; oh.w = th[d][s4 + 3];
    ol.x = tl[d][s4 + 0]; ol.y = tl[d][s4 + 1];
    ol.z = tl[d][s4 + 2]; ol.w = tl[d][s4 + 3];
    size_t o = (size_t)(h * H_DIM + d) * S_LEN + s0 + s4;
    *reinterpret_cast<ushort4*>(&Vth[o]) = oh;
    *reinterpret_cast<ushort4*>(&Vtl[o]) = ol;
  }
}

// ============================================================================
// Flash attention fwd (causal) via bf16x3 MFMA, fp32 online softmax.
// Block: 1 head x 64 q-rows, 4 waves x 16 rows. T14 prefetch in NAMED regs.
// ============================================================================
__global__ __launch_bounds__(256)
void attn_mfma(const ushort* __restrict__ Qh_g, const ushort* __restrict__ Ql_g,
               const ushort* __restrict__ Kh_g, const ushort* __restrict__ Kl_g,
               const ushort* __restrict__ Vh_g, const ushort* __restrict__ Vl_g,
               ushort* __restrict__ CTXh, ushort* __restrict__ CTXl) {
  __shared__ __align__(16) ushort Kh_s[64 * 64];
  __shared__ __align__(16) ushort Kl_s[64 * 64];
  __shared__ __align__(16) ushort Vh_s[64 * 64];
  __shared__ __align__(16) ushort Vl_s[64 * 64];
  __shared__ unsigned int P_s[4][16 * 68];  // per-wave, packed hi|lo

  char* KhB = (char*)Kh_s;
  char* KlB = (char*)Kl_s;
  char* VhB = (char*)Vh_s;
  char* VlB = (char*)Vl_s;

  const int tid  = threadIdx.x;
  const int lane = tid & 63;
  const int w    = tid >> 6;
  const int qb   = gridDim.x - 1 - blockIdx.x;  // big-work blocks first
  const int h    = blockIdx.y;
  const int lr   = lane & 15;
  const int lk   = lane >> 4;
  const float NEG = -1e30f;

  const int r0 = tid >> 3;          // 0..31
  const int cb = (tid & 7) * 16;
  const int ce = (tid & 7) * 8;
  const int swA = SWZ(r0, cb);
  const int swB = SWZ(r0 + 32, cb);

  // ---- Prologue: stage Q tile through K buffers, hoist A-frags to regs ----
  {
    size_t g0 = (size_t)(qb * 64 + r0) * D_MODEL + h * H_DIM + ce;
    size_t g1 = g0 + 32 * (size_t)D_MODEL;
    *reinterpret_cast<float4*>(KhB + swA) =
        *reinterpret_cast<const float4*>(Qh_g + g0);
    *reinterpret_cast<float4*>(KhB + swB) =
        *reinterpret_cast<const float4*>(Qh_g + g1);
    *reinterpret_cast<float4*>(KlB + swA) =
        *reinterpret_cast<const float4*>(Ql_g + g0);
    *reinterpret_cast<float4*>(KlB + swB) =
        *reinterpret_cast<const float4*>(Ql_g + g1);
  }
  __syncthreads();
  short8 aqh[2], aql[2];
#pragma unroll
  for (int kc = 0; kc < 2; ++kc) {
    int ao = SWZ(w * 16 + lr, kc * 64 + lk * 16);
    aqh[kc] = *reinterpret_cast<const short8*>(KhB + ao);
    aql[kc] = *reinterpret_cast<const short8*>(KlB + ao);
  }

  f32x4 o[4];
  float m[4], l[4];
#pragma unroll
  for (int t = 0; t < 4; ++t) o[t] = {0.f, 0.f, 0.f, 0.f};
#pragma unroll
  for (int r = 0; r < 4; ++r) { m[r] = NEG; l[r] = 0.f; }

  // T14 prefetch: named registers only.
  float4 gkh0, gkh1, gkl0, gkl1, gvh0, gvh1, gvl0, gvl1;

#define ATTN_ISSUE(kt_)                                                     \
  {                                                                         \
    size_t gk0 = (size_t)((kt_) * 64 + r0) * D_MODEL + h * H_DIM + ce;      \
    size_t gk1 = gk0 + 32 * (size_t)D_MODEL;                                \
    size_t gv0 = (size_t)(h * H_DIM + r0) * S_LEN + (kt_) * 64 + ce;        \
    size_t gv1 = gv0 + 32 * (size_t)S_LEN;                                  \
    gkh0 = *reinterpret_cast<const float4*>(Kh_g + gk0);                    \
    gkh1 = *reinterpret_cast<const float4*>(Kh_g + gk1);                    \
    gkl0 = *reinterpret_cast<const float4*>(Kl_g + gk0);                    \
    gkl1 = *reinterpret_cast<const float4*>(Kl_g + gk1);                    \
    gvh0 = *reinterpret_cast<const float4*>(Vh_g + gv0);                    \
    gvh1 = *reinterpret_cast<const float4*>(Vh_g + gv1);                    \
    gvl0 = *reinterpret_cast<const float4*>(Vl_g + gv0);                    \
    gvl1 = *reinterpret_cast<const float4*>(Vl_g + gv1);                    \
  }

  ATTN_ISSUE(0);

  for (int kt = 0; kt <= qb; ++kt) {
    __syncthreads();  // prior tile's LDS reads done (covers Q-frag reads too)
    *reinterpret_cast<float4*>(KhB + swA) = gkh0;
    *reinterpret_cast<float4*>(KhB + swB) = gkh1;
    *reinterpret_cast<float4*>(KlB + swA) = gkl0;
    *reinterpret_cast<float4*>(KlB + swB) = gkl1;
    *reinterpret_cast<float4*>(VhB + swA) = gvh0;
    *reinterpret_cast<float4*>(VhB + swB) = gvh1;
    *reinterpret_cast<float4*>(VlB + swA) = gvl0;
    *reinterpret_cast<float4*>(VlB + swB) = gvl1;
    __syncthreads();
    if (kt < qb) ATTN_ISSUE(kt + 1);  // in flight during compute

    // ---- S = Q K^T (bf16x3) ----
    f32x4 sacc[4];
#pragma unroll
    for (int t = 0; t < 4; ++t) sacc[t] = {0.f, 0.f, 0.f, 0.f};
#pragma unroll
    for (int kc = 0; kc < 2; ++kc) {
#pragma unroll
      for (int t = 0; t < 4; ++t) {
        int bo = SWZ(t * 16 + lr, kc * 64 + lk * 16);
        short8 bh = *reinterpret_cast<const short8*>(KhB + bo);
        short8 bl = *reinterpret_cast<const short8*>(KlB + bo);
        sacc[t] = __builtin_amdgcn_mfma_f32_16x16x32_bf16(aqh[kc], bh, sacc[t], 0, 0, 0);
        sacc[t] = __builtin_amdgcn_mfma_f32_16x16x32_bf16(aql[kc], bh, sacc[t], 0, 0, 0);
        sacc[t] = __builtin_amdgcn_mfma_f32_16x16x32_bf16(aqh[kc], bl, sacc[t], 0, 0, 0);
      }
    }

    // ---- causal mask on the diagonal tile ----
    if (kt == qb) {
#pragma unroll
      for (int t = 0; t < 4; ++t) {
        int colg = t * 16 + lr;
#pragma unroll
        for (int r = 0; r < 4; ++r) {
          int rowg = w * 16 + lk * 4 + r;
          if (colg > rowg) sacc[t][r] = NEG;
        }
      }
    }

    // ---- online softmax (rows live in 16-lane groups) ----
    float pf[4][4];  // [t][r]
#pragma unroll
    for (int r = 0; r < 4; ++r) {
      float mx = fmaxf(fmaxf(sacc[0][r], sacc[1][r]),
                       fmaxf(sacc[2][r], sacc[3][r]));
      mx = fmaxf(mx, __shfl_xor(mx, 1));
      mx = fmaxf(mx, __shfl_xor(mx, 2));
      mx = fmaxf(mx, __shfl_xor(mx, 4));
      mx = fmaxf(mx, __shfl_xor(mx, 8));
      float mnew  = fmaxf(m[r], mx);
      float alpha = __expf(m[r] - mnew);
      float rs = 0.f;
#pragma unroll
      for (int t = 0; t < 4; ++t) {
        float p = __expf(sacc[t][r] - mnew);
        pf[t][r] = p;
        rs += p;
      }
      rs += __shfl_xor(rs, 1);
      rs += __shfl_xor(rs, 2);
      rs += __shfl_xor(rs, 4);
      rs += __shfl_xor(rs, 8);
      l[r] = l[r] * alpha + rs;
      m[r] = mnew;
#pragma unroll
      for (int t = 0; t < 4; ++t) o[t][r] *= alpha;
    }

    // ---- P -> per-wave LDS (packed hi|lo u32) ----
    unsigned int* pw = P_s[w];
#pragma unroll
    for (int r = 0; r < 4; ++r) {
#pragma unroll
      for (int t = 0; t < 4; ++t) {
        float p = pf[t][r];
        ushort ph = f2bh(p);
        ushort pl = f2bh(p - bh2f(ph));
        pw[(lk * 4 + r) * 68 + t * 16 + lr] =
            (unsigned)ph | ((unsigned)pl << 16);
      }
    }

    // ---- O += P V (bf16x3) ----
#pragma unroll
    for (int kc = 0; kc < 2; ++kc) {
      const uint4* pp = reinterpret_cast<const uint4*>(
          &pw[lr * 68 + kc * 32 + lk * 8]);
      uint4 u0 = pp[0];
      uint4 u1 = pp[1];
      short8 pah, pal;
      pah[0] = (short)(u0.x & 0xffff); pal[0] = (short)(u0.x >> 16);
      pah[1] = (short)(u0.y & 0xffff); pal[1] = (short)(u0.y >> 16);
      pah[2] = (short)(u0.z & 0xffff); pal[2] = (short)(u0.z >> 16);
      pah[3] = (short)(u0.w & 0xffff); pal[3] = (short)(u0.w >> 16);
      pah[4] = (short)(u1.x & 0xffff); pal[4] = (short)(u1.x >> 16);
      pah[5] = (short)(u1.y & 0xffff); pal[5] = (short)(u1.y >> 16);
      pah[6] = (short)(u1.z & 0xffff); pal[6] = (short)(u1.z >> 16);
      pah[7] = (short)(u1.w & 0xffff); pal[7] = (short)(u1.w >> 16);
#pragma unroll
      for (int t = 0; t < 4; ++t) {
        int bo = SWZ(t * 16 + lr, kc * 64 + lk * 16);
        short8 vh = *reinterpret_cast<const short8*>(VhB + bo);
        short8 vl = *reinterpret_cast<const short8*>(VlB + bo);
        o[t] = __builtin_amdgcn_mfma_f32_16x16x32_bf16(pah, vh, o[t], 0, 0, 0);
        o[t] = __builtin_amdgcn_mfma_f32_16x16x32_bf16(pah, vl, o[t], 0, 0, 0);
        o[t] = __builtin_amdgcn_mfma_f32_16x16x32_bf16(pal, vh, o[t], 0, 0, 0);
      }
    }
  }
#undef ATTN_ISSUE

  // ---- epilogue: normalize, store ctx as hi/lo bf16 planes ----
  float inv[4];
#pragma unroll
  for (int r = 0; r < 4; ++r) inv[r] = 1.f / l[r];
#pragma unroll
  for (int t = 0; t < 4; ++t)
#pragma unroll
    for (int r = 0; r < 4; ++r) {
      size_t idx = (size_t)(qb * 64 + w * 16 + lk * 4 + r) * D_MODEL +
                   h * H_DIM + t * 16 + lr;
      float v = o[t][r] * inv[r];
      ushort hh = f2bh(v);
      CTXh[idx] = hh;
      CTXl[idx] = f2bh(v - bh2f(hh));
    }
}

// ============================================================================
extern "C" void kernel_launch(void* const* d_in, const int* in_sizes, int n_in,
                              void* d_out, int out_size, void* d_ws,
                              size_t ws_size, hipStream_t stream) {
  // setup_inputs order: x, w_k, w_q, w_v, w_o, b_o
  const float* x  = (const float*)d_in[0];
  const float* wk = (const float*)d_in[1];
  const float* wq = (const float*)d_in[2];
  const float* wv = (const float*)d_in[3];
  const float* wo = (const float*)d_in[4];
  const float* bo = (const float*)d_in[5];
  float* out = (float*)d_out;

  // Workspace layout (ushort elements):
  ushort* xh   = (ushort*)d_ws;
  ushort* xl   = xh + NELEM;
  ushort* WH   = xl + NELEM;          // 4 planes: q,k,v,o
  ushort* WL   = WH + 4 * (size_t)WELEM;
  ushort* QKV  = WL + 4 * (size_t)WELEM;  // [Qh][Ql][Kh][Kl][Vrh][Vrl]
  ushort* Qh   = QKV;
  ushort* Ql   = Qh + NELEM;
  ushort* Kh   = Ql + NELEM;
  ushort* Kl   = Kh + NELEM;
  ushort* Vrh  = Kl + NELEM;
  ushort* Vrl  = Vrh + NELEM;
  ushort* Vth  = Vrl + NELEM;
  ushort* Vtl  = Vth + NELEM;
  ushort* CTXh = Vtl + NELEM;
  ushort* CTXl = CTXh + NELEM;

  dim3 blk(256);
  convert_x<<<dim3(NELEM / 4 / 256), blk, 0, stream>>>(x, xh, xl);
  convert_w<<<dim3(WELEM / 4 / 256, 1, 4), blk, 0, stream>>>(wq, wk, wv, wo,
                                                             WH, WL);
  gemm_qkv_bf3<<<dim3(D_MODEL / 64, S_LEN / 128, 3), blk, 0, stream>>>(
      xh, xl, WH, WL, QKV);
  convert_vt<<<dim3(S_LEN / 64, N_HEAD), blk, 0, stream>>>(Vrh, Vrl, Vth, Vtl);
  attn_mfma<<<dim3(S_LEN / 64, N_HEAD), blk, 0, stream>>>(
      Qh, Ql, Kh, Kl, Vth, Vtl, CTXh, CTXl);
  gemm_out_bf3<<<dim3(D_MODEL / 64, S_LEN / 128, 1), blk, 0, stream>>>(
      CTXh, CTXl, WH + 3 * (size_t)WELEM, WL + 3 * (size_t)WELEM, bo, out);
}

// Round 5
// 361.534 us; speedup vs baseline: 2.5516x; 1.1704x over previous
//
#include <hip/hip_runtime.h>
#include <math.h>

// Problem constants (B=1)
#define S_LEN   4096
#define D_MODEL 768
#define N_HEAD  12
#define H_DIM   64
#define NELEM   (S_LEN * D_MODEL)    // 3,145,728
#define WELEM   (D_MODEL * D_MODEL)  // 589,824

typedef unsigned short ushort;
typedef __attribute__((ext_vector_type(8))) short short8;
typedef __attribute__((ext_vector_type(4))) float f32x4;

__device__ __forceinline__ ushort f2bh(float f) {
  unsigned u = __float_as_uint(f);
  u += 0x7fffu + ((u >> 16) & 1u);  // round-to-nearest-even
  return (ushort)(u >> 16);
}
__device__ __forceinline__ float bh2f(ushort h) {
  return __uint_as_float(((unsigned)h) << 16);
}

// XOR swizzle for 64-bf16 (128B) LDS rows: spreads 16B slots across banks.
#define SWZ(row, colByte) ((((row) * 128) + (colByte)) ^ (((row) & 7) << 4))

// ============================================================================
// convert_x: fp32 -> bf16 hi/lo planes (element-wise, 4/thread)
// ============================================================================
__global__ __launch_bounds__(256)
void convert_x(const float* __restrict__ x, ushort* __restrict__ xh,
               ushort* __restrict__ xl) {
  size_t i = ((size_t)blockIdx.x * 256 + threadIdx.x) * 4;
  float4 v = *reinterpret_cast<const float4*>(&x[i]);
  ushort4 hv, lv;
  hv.x = f2bh(v.x); lv.x = f2bh(v.x - bh2f(hv.x));
  hv.y = f2bh(v.y); lv.y = f2bh(v.y - bh2f(hv.y));
  hv.z = f2bh(v.z); lv.z = f2bh(v.z - bh2f(hv.z));
  hv.w = f2bh(v.w); lv.w = f2bh(v.w - bh2f(hv.w));
  *reinterpret_cast<ushort4*>(&xh[i]) = hv;
  *reinterpret_cast<ushort4*>(&xl[i]) = lv;
}

// convert_w: 4 weight matrices -> hi/lo planes (plane z: 0=q,1=k,2=v,3=o)
__global__ __launch_bounds__(256)
void convert_w(const float* __restrict__ wq, const float* __restrict__ wk,
               const float* __restrict__ wv, const float* __restrict__ wo,
               ushort* __restrict__ WH, ushort* __restrict__ WL) {
  int z = blockIdx.z;
  const float* src = (z == 0) ? wq : (z == 1) ? wk : (z == 2) ? wv : wo;
  ushort* oh = WH + (size_t)z * WELEM;
  ushort* ol = WL + (size_t)z * WELEM;
  size_t i = ((size_t)blockIdx.x * 256 + threadIdx.x) * 4;
  float4 v = *reinterpret_cast<const float4*>(&src[i]);
  ushort4 hv, lv;
  hv.x = f2bh(v.x); lv.x = f2bh(v.x - bh2f(hv.x));
  hv.y = f2bh(v.y); lv.y = f2bh(v.y - bh2f(hv.y));
  hv.z = f2bh(v.z); lv.z = f2bh(v.z - bh2f(hv.z));
  hv.w = f2bh(v.w); lv.w = f2bh(v.w - bh2f(hv.w));
  *reinterpret_cast<ushort4*>(&oh[i]) = hv;
  *reinterpret_cast<ushort4*>(&ol[i]) = lv;
}

// ============================================================================
// bf16x3 MFMA GEMM core: C[128x64] += A(hi+lo) * W(hi+lo)^T
// 256 thr = 4 waves (2x2); wave = 64x32 sub-tile = 4x2 16x16 frags.
// BK=64, swizzled LDS. T14 prefetch in NAMED registers (arrays/lambdas go to
// scratch -- R3 lesson: 500MB HBM writes).
// ============================================================================
__device__ __forceinline__ void gemm_bf3_core(
    const ushort* __restrict__ Ah, const ushort* __restrict__ Al,
    const ushort* __restrict__ Wh, const ushort* __restrict__ Wl,
    int rowbase, int colbase, f32x4 (&acc)[4][2]) {
  __shared__ __align__(16) ushort AhS[128 * 64];
  __shared__ __align__(16) ushort AlS[128 * 64];
  __shared__ __align__(16) ushort WhS[64 * 64];
  __shared__ __align__(16) ushort WlS[64 * 64];
  char* AhB = (char*)AhS; char* AlB = (char*)AlS;
  char* WhB = (char*)WhS; char* WlB = (char*)WlS;

  const int tid  = threadIdx.x;
  const int lane = tid & 63;
  const int w    = tid >> 6;
  const int wm   = w >> 1;
  const int wn   = w & 1;
  const int lr   = lane & 15;
  const int lk   = lane >> 4;

  const int r0 = tid >> 3;          // 0..31
  const int cb = (tid & 7) * 16;    // byte col in LDS row
  const int ce = (tid & 7) * 8;     // element col
  const int sA0 = SWZ(r0, cb);
  const int sA1 = SWZ(r0 + 32, cb);
  const int sA2 = SWZ(r0 + 64, cb);
  const int sA3 = SWZ(r0 + 96, cb);

#pragma unroll
  for (int mt = 0; mt < 4; ++mt)
#pragma unroll
    for (int nt = 0; nt < 2; ++nt) acc[mt][nt] = {0.f, 0.f, 0.f, 0.f};

  // Named prefetch registers (A: 4 row-groups x hi/lo; W: 2 x hi/lo).
  float4 gA0h, gA1h, gA2h, gA3h, gA0l, gA1l, gA2l, gA3l;
  float4 gW0h, gW1h, gW0l, gW1l;

#define GEMM_ISSUE(k0_)                                                     \
  {                                                                         \
    size_t oA = (size_t)(rowbase + r0) * D_MODEL + (k0_) + ce;              \
    const size_t st = 32 * (size_t)D_MODEL;                                 \
    gA0h = *reinterpret_cast<const float4*>(Ah + oA);                       \
    gA1h = *reinterpret_cast<const float4*>(Ah + oA + st);                  \
    gA2h = *reinterpret_cast<const float4*>(Ah + oA + 2 * st);              \
    gA3h = *reinterpret_cast<const float4*>(Ah + oA + 3 * st);              \
    gA0l = *reinterpret_cast<const float4*>(Al + oA);                       \
    gA1l = *reinterpret_cast<const float4*>(Al + oA + st);                  \
    gA2l = *reinterpret_cast<const float4*>(Al + oA + 2 * st);              \
    gA3l = *reinterpret_cast<const float4*>(Al + oA + 3 * st);              \
    size_t oW = (size_t)(colbase + r0) * D_MODEL + (k0_) + ce;              \
    gW0h = *reinterpret_cast<const float4*>(Wh + oW);                       \
    gW1h = *reinterpret_cast<const float4*>(Wh + oW + st);                  \
    gW0l = *reinterpret_cast<const float4*>(Wl + oW);                       \
    gW1l = *reinterpret_cast<const float4*>(Wl + oW + st);                  \
  }

  GEMM_ISSUE(0);
  for (int ks = 0; ks < D_MODEL / 64; ++ks) {
    __syncthreads();  // prior compute done reading LDS
    *reinterpret_cast<float4*>(AhB + sA0) = gA0h;
    *reinterpret_cast<float4*>(AhB + sA1) = gA1h;
    *reinterpret_cast<float4*>(AhB + sA2) = gA2h;
    *reinterpret_cast<float4*>(AhB + sA3) = gA3h;
    *reinterpret_cast<float4*>(AlB + sA0) = gA0l;
    *reinterpret_cast<float4*>(AlB + sA1) = gA1l;
    *reinterpret_cast<float4*>(AlB + sA2) = gA2l;
    *reinterpret_cast<float4*>(AlB + sA3) = gA3l;
    *reinterpret_cast<float4*>(WhB + sA0) = gW0h;
    *reinterpret_cast<float4*>(WhB + sA1) = gW1h;
    *reinterpret_cast<float4*>(WlB + sA0) = gW0l;
    *reinterpret_cast<float4*>(WlB + sA1) = gW1l;
    __syncthreads();
    if (ks < D_MODEL / 64 - 1) GEMM_ISSUE((ks + 1) * 64);  // hide under MFMA

#pragma unroll
    for (int kc = 0; kc < 2; ++kc) {
      short8 ah[4], al[4], bh[2], bl[2];
#pragma unroll
      for (int mt = 0; mt < 4; ++mt) {
        int o = SWZ(wm * 64 + mt * 16 + lr, kc * 64 + lk * 16);
        ah[mt] = *reinterpret_cast<const short8*>(AhB + o);
        al[mt] = *reinterpret_cast<const short8*>(AlB + o);
      }
#pragma unroll
      for (int nt = 0; nt < 2; ++nt) {
        int o = SWZ(wn * 32 + nt * 16 + lr, kc * 64 + lk * 16);
        bh[nt] = *reinterpret_cast<const short8*>(WhB + o);
        bl[nt] = *reinterpret_cast<const short8*>(WlB + o);
      }
#pragma unroll
      for (int mt = 0; mt < 4; ++mt)
#pragma unroll
        for (int nt = 0; nt < 2; ++nt) {
          acc[mt][nt] = __builtin_amdgcn_mfma_f32_16x16x32_bf16(
              ah[mt], bh[nt], acc[mt][nt], 0, 0, 0);
          acc[mt][nt] = __builtin_amdgcn_mfma_f32_16x16x32_bf16(
              al[mt], bh[nt], acc[mt][nt], 0, 0, 0);
          acc[mt][nt] = __builtin_amdgcn_mfma_f32_16x16x32_bf16(
              ah[mt], bl[nt], acc[mt][nt], 0, 0, 0);
        }
    }
  }
#undef GEMM_ISSUE
}

// QKV projections: grid (12, 32, 3); z: 0=Q(scale 1/8), 1=K, 2=V.
__global__ __launch_bounds__(256)
void gemm_qkv_bf3(const ushort* __restrict__ xh, const ushort* __restrict__ xl,
                  const ushort* __restrict__ WH, const ushort* __restrict__ WL,
                  ushort* __restrict__ QKV) {
  const int z = blockIdx.z;
  const ushort* Wh = WH + (size_t)z * WELEM;
  const ushort* Wl = WL + (size_t)z * WELEM;
  ushort* oh = QKV + (size_t)z * (2 * NELEM);
  ushort* ol = oh + NELEM;
  const float scale = (z == 0) ? 0.125f : 1.0f;
  const int rowbase = blockIdx.y * 128;
  const int colbase = blockIdx.x * 64;

  f32x4 acc[4][2];
  gemm_bf3_core(xh, xl, Wh, Wl, rowbase, colbase, acc);

  const int lane = threadIdx.x & 63, w = threadIdx.x >> 6;
  const int wm = w >> 1, wn = w & 1, lr = lane & 15, lk = lane >> 4;
#pragma unroll
  for (int mt = 0; mt < 4; ++mt)
#pragma unroll
    for (int nt = 0; nt < 2; ++nt)
#pragma unroll
      for (int j = 0; j < 4; ++j) {
        int rg = rowbase + wm * 64 + mt * 16 + lk * 4 + j;
        int cg = colbase + wn * 32 + nt * 16 + lr;
        float v = acc[mt][nt][j] * scale;
        ushort hh = f2bh(v);
        oh[(size_t)rg * D_MODEL + cg] = hh;
        ol[(size_t)rg * D_MODEL + cg] = f2bh(v - bh2f(hh));
      }
}

// Output projection: fp32 out + bias.
__global__ __launch_bounds__(256)
void gemm_out_bf3(const ushort* __restrict__ ch, const ushort* __restrict__ cl,
                  const ushort* __restrict__ woh, const ushort* __restrict__ wol,
                  const float* __restrict__ bo, float* __restrict__ out) {
  const int rowbase = blockIdx.y * 128;
  const int colbase = blockIdx.x * 64;
  f32x4 acc[4][2];
  gemm_bf3_core(ch, cl, woh, wol, rowbase, colbase, acc);

  const int lane = threadIdx.x & 63, w = threadIdx.x >> 6;
  const int wm = w >> 1, wn = w & 1, lr = lane & 15, lk = lane >> 4;
#pragma unroll
  for (int nt = 0; nt < 2; ++nt) {
    int cg = colbase + wn * 32 + nt * 16 + lr;
    float bb = bo[cg];
#pragma unroll
    for (int mt = 0; mt < 4; ++mt)
#pragma unroll
      for (int j = 0; j < 4; ++j) {
        int rg = rowbase + wm * 64 + mt * 16 + lk * 4 + j;
        out[(size_t)rg * D_MODEL + cg] = acc[mt][nt][j] + bb;
      }
  }
}

// ============================================================================
// V transpose: row-major hi/lo planes -> [h][d][s] hi/lo planes.
// ============================================================================
__global__ __launch_bounds__(256)
void convert_vt(const ushort* __restrict__ Vrh, const ushort* __restrict__ Vrl,
                ushort* __restrict__ Vth, ushort* __restrict__ Vtl) {
  __shared__ ushort th[64][68];
  __shared__ ushort tl[64][68];
  const int tid = threadIdx.x;
  const int s0  = blockIdx.x * 64;
  const int h   = blockIdx.y;
#pragma unroll
  for (int it = 0; it < 4; ++it) {
    int id = tid + it * 256;
    int s  = id >> 4;
    int c4 = (id & 15) * 4;
    size_t g = (size_t)(s0 + s) * D_MODEL + h * H_DIM + c4;
    ushort4 vh = *reinterpret_cast<const ushort4*>(&Vrh[g]);
    ushort4 vl = *reinterpret_cast<const ushort4*>(&Vrl[g]);
    th[c4 + 0][s] = vh.x; th[c4 + 1][s] = vh.y;
    th[c4 + 2][s] = vh.z; th[c4 + 3][s] = vh.w;
    tl[c4 + 0][s] = vl.x; tl[c4 + 1][s] = vl.y;
    tl[c4 + 2][s] = vl.z; tl[c4 + 3][s] = vl.w;
  }
  __syncthreads();
#pragma unroll
  for (int it = 0; it < 4; ++it) {
    int id = tid + it * 256;
    int d  = id >> 4;
    int s4 = (id & 15) * 4;
    ushort4 oh, ol;
    oh.x = th[d][s4 + 0]; oh.y = th[d][s4 + 1];
    oh.z = th[d][s4 + 2]; oh.w = th[d][s4 + 3];
    ol.x = tl[d][s4 + 0]; ol.y = tl[d][s4 + 1];
    ol.z = tl[d][s4 + 2]; ol.w = tl[d][s4 + 3];
    size_t o = (size_t)(h * H_DIM + d) * S_LEN + s0 + s4;
    *reinterpret_cast<ushort4*>(&Vth[o]) = oh;
    *reinterpret_cast<ushort4*>(&Vtl[o]) = ol;
  }
}

// ============================================================================
// Flash attention fwd (causal), bf16x3 MFMA, fp32 online softmax, SPLIT-K.
// Grid (96, 12):
//   bx  0..31: qb=63-bx,      kt [0,32)      -> partial slot c=0  (32 tiles)
//   bx 32..63: qb=63-(bx-32), kt [32,qb+1)   -> partial slot c=1  (1..32)
//   bx 64..95: qb=95-bx,      kt [0,qb+1)    -> direct CTX write  (1..32)
// Partials (qb>=32 only): unnormalized fp32 O[64][64] + m[64] + l[64].
// ============================================================================
__global__ __launch_bounds__(256)
void attn_mfma(const ushort* __restrict__ Qh_g, const ushort* __restrict__ Ql_g,
               const ushort* __restrict__ Kh_g, const ushort* __restrict__ Kl_g,
               const ushort* __restrict__ Vh_g, const ushort* __restrict__ Vl_g,
               ushort* __restrict__ CTXh, ushort* __restrict__ CTXl,
               float* __restrict__ O_part, float* __restrict__ m_part,
               float* __restrict__ l_part) {
  __shared__ __align__(16) ushort Kh_s[64 * 64];
  __shared__ __align__(16) ushort Kl_s[64 * 64];
  __shared__ __align__(16) ushort Vh_s[64 * 64];
  __shared__ __align__(16) ushort Vl_s[64 * 64];
  __shared__ unsigned int P_s[4][16 * 68];  // per-wave, packed hi|lo

  char* KhB = (char*)Kh_s;
  char* KlB = (char*)Kl_s;
  char* VhB = (char*)Vh_s;
  char* VlB = (char*)Vl_s;

  const int tid  = threadIdx.x;
  const int lane = tid & 63;
  const int w    = tid >> 6;
  const int h    = blockIdx.y;
  const int lr   = lane & 15;
  const int lk   = lane >> 4;
  const float NEG = -1e30f;

  // Work assignment (heavy chunks dispatched first).
  const int bx = blockIdx.x;
  int qb, kt0, kt1, cidx, partial;
  if (bx < 32)      { qb = 63 - bx;        kt0 = 0;  kt1 = 32;     cidx = 0; partial = 1; }
  else if (bx < 64) { qb = 63 - (bx - 32); kt0 = 32; kt1 = qb + 1; cidx = 1; partial = 1; }
  else              { qb = 95 - bx;        kt0 = 0;  kt1 = qb + 1; cidx = 0; partial = 0; }

  const int r0 = tid >> 3;          // 0..31
  const int cb = (tid & 7) * 16;
  const int ce = (tid & 7) * 8;
  const int swA = SWZ(r0, cb);
  const int swB = SWZ(r0 + 32, cb);

  // ---- Prologue: stage Q tile through K buffers, hoist A-frags to regs ----
  {
    size_t g0 = (size_t)(qb * 64 + r0) * D_MODEL + h * H_DIM + ce;
    size_t g1 = g0 + 32 * (size_t)D_MODEL;
    *reinterpret_cast<float4*>(KhB + swA) =
        *reinterpret_cast<const float4*>(Qh_g + g0);
    *reinterpret_cast<float4*>(KhB + swB) =
        *reinterpret_cast<const float4*>(Qh_g + g1);
    *reinterpret_cast<float4*>(KlB + swA) =
        *reinterpret_cast<const float4*>(Ql_g + g0);
    *reinterpret_cast<float4*>(KlB + swB) =
        *reinterpret_cast<const float4*>(Ql_g + g1);
  }
  __syncthreads();
  short8 aqh[2], aql[2];
#pragma unroll
  for (int kc = 0; kc < 2; ++kc) {
    int ao = SWZ(w * 16 + lr, kc * 64 + lk * 16);
    aqh[kc] = *reinterpret_cast<const short8*>(KhB + ao);
    aql[kc] = *reinterpret_cast<const short8*>(KlB + ao);
  }

  f32x4 o[4];
  float m[4], l[4];
#pragma unroll
  for (int t = 0; t < 4; ++t) o[t] = {0.f, 0.f, 0.f, 0.f};
#pragma unroll
  for (int r = 0; r < 4; ++r) { m[r] = NEG; l[r] = 0.f; }

  // T14 prefetch: named registers only.
  float4 gkh0, gkh1, gkl0, gkl1, gvh0, gvh1, gvl0, gvl1;

#define ATTN_ISSUE(kt_)                                                     \
  {                                                                         \
    size_t gk0 = (size_t)((kt_) * 64 + r0) * D_MODEL + h * H_DIM + ce;      \
    size_t gk1 = gk0 + 32 * (size_t)D_MODEL;                                \
    size_t gv0 = (size_t)(h * H_DIM + r0) * S_LEN + (kt_) * 64 + ce;        \
    size_t gv1 = gv0 + 32 * (size_t)S_LEN;                                  \
    gkh0 = *reinterpret_cast<const float4*>(Kh_g + gk0);                    \
    gkh1 = *reinterpret_cast<const float4*>(Kh_g + gk1);                    \
    gkl0 = *reinterpret_cast<const float4*>(Kl_g + gk0);                    \
    gkl1 = *reinterpret_cast<const float4*>(Kl_g + gk1);                    \
    gvh0 = *reinterpret_cast<const float4*>(Vh_g + gv0);                    \
    gvh1 = *reinterpret_cast<const float4*>(Vh_g + gv1);                    \
    gvl0 = *reinterpret_cast<const float4*>(Vl_g + gv0);                    \
    gvl1 = *reinterpret_cast<const float4*>(Vl_g + gv1);                    \
  }

  ATTN_ISSUE(kt0);

  for (int kt = kt0; kt < kt1; ++kt) {
    __syncthreads();  // prior tile's LDS reads done (covers Q-frag reads too)
    *reinterpret_cast<float4*>(KhB + swA) = gkh0;
    *reinterpret_cast<float4*>(KhB + swB) = gkh1;
    *reinterpret_cast<float4*>(KlB + swA) = gkl0;
    *reinterpret_cast<float4*>(KlB + swB) = gkl1;
    *reinterpret_cast<float4*>(VhB + swA) = gvh0;
    *reinterpret_cast<float4*>(VhB + swB) = gvh1;
    *reinterpret_cast<float4*>(VlB + swA) = gvl0;
    *reinterpret_cast<float4*>(VlB + swB) = gvl1;
    __syncthreads();
    if (kt + 1 < kt1) ATTN_ISSUE(kt + 1);  // in flight during compute

    // ---- S = Q K^T (bf16x3) ----
    f32x4 sacc[4];
#pragma unroll
    for (int t = 0; t < 4; ++t) sacc[t] = {0.f, 0.f, 0.f, 0.f};
#pragma unroll
    for (int kc = 0; kc < 2; ++kc) {
#pragma unroll
      for (int t = 0; t < 4; ++t) {
        int bo = SWZ(t * 16 + lr, kc * 64 + lk * 16);
        short8 bh = *reinterpret_cast<const short8*>(KhB + bo);
        short8 bl = *reinterpret_cast<const short8*>(KlB + bo);
        sacc[t] = __builtin_amdgcn_mfma_f32_16x16x32_bf16(aqh[kc], bh, sacc[t], 0, 0, 0);
        sacc[t] = __builtin_amdgcn_mfma_f32_16x16x32_bf16(aql[kc], bh, sacc[t], 0, 0, 0);
        sacc[t] = __builtin_amdgcn_mfma_f32_16x16x32_bf16(aqh[kc], bl, sacc[t], 0, 0, 0);
      }
    }

    // ---- causal mask on the diagonal tile ----
    if (kt == qb) {
#pragma unroll
      for (int t = 0; t < 4; ++t) {
        int colg = t * 16 + lr;
#pragma unroll
        for (int r = 0; r < 4; ++r) {
          int rowg = w * 16 + lk * 4 + r;
          if (colg > rowg) sacc[t][r] = NEG;
        }
      }
    }

    // ---- online softmax (rows live in 16-lane groups) ----
    float pf[4][4];  // [t][r]
#pragma unroll
    for (int r = 0; r < 4; ++r) {
      float mx = fmaxf(fmaxf(sacc[0][r], sacc[1][r]),
                       fmaxf(sacc[2][r], sacc[3][r]));
      mx = fmaxf(mx, __shfl_xor(mx, 1));
      mx = fmaxf(mx, __shfl_xor(mx, 2));
      mx = fmaxf(mx, __shfl_xor(mx, 4));
      mx = fmaxf(mx, __shfl_xor(mx, 8));
      float mnew  = fmaxf(m[r], mx);
      float alpha = __expf(m[r] - mnew);
      float rs = 0.f;
#pragma unroll
      for (int t = 0; t < 4; ++t) {
        float p = __expf(sacc[t][r] - mnew);
        pf[t][r] = p;
        rs += p;
      }
      rs += __shfl_xor(rs, 1);
      rs += __shfl_xor(rs, 2);
      rs += __shfl_xor(rs, 4);
      rs += __shfl_xor(rs, 8);
      l[r] = l[r] * alpha + rs;
      m[r] = mnew;
#pragma unroll
      for (int t = 0; t < 4; ++t) o[t][r] *= alpha;
    }

    // ---- P -> per-wave LDS (packed hi|lo u32) ----
    unsigned int* pw = P_s[w];
#pragma unroll
    for (int r = 0; r < 4; ++r) {
#pragma unroll
      for (int t = 0; t < 4; ++t) {
        float p = pf[t][r];
        ushort ph = f2bh(p);
        ushort pl = f2bh(p - bh2f(ph));
        pw[(lk * 4 + r) * 68 + t * 16 + lr] =
            (unsigned)ph | ((unsigned)pl << 16);
      }
    }

    // ---- O += P V (bf16x3) ----
#pragma unroll
    for (int kc = 0; kc < 2; ++kc) {
      const uint4* pp = reinterpret_cast<const uint4*>(
          &pw[lr * 68 + kc * 32 + lk * 8]);
      uint4 u0 = pp[0];
      uint4 u1 = pp[1];
      short8 pah, pal;
      pah[0] = (short)(u0.x & 0xffff); pal[0] = (short)(u0.x >> 16);
      pah[1] = (short)(u0.y & 0xffff); pal[1] = (short)(u0.y >> 16);
      pah[2] = (short)(u0.z & 0xffff); pal[2] = (short)(u0.z >> 16);
      pah[3] = (short)(u0.w & 0xffff); pal[3] = (short)(u0.w >> 16);
      pah[4] = (short)(u1.x & 0xffff); pal[4] = (short)(u1.x >> 16);
      pah[5] = (short)(u1.y & 0xffff); pal[5] = (short)(u1.y >> 16);
      pah[6] = (short)(u1.z & 0xffff); pal[6] = (short)(u1.z >> 16);
      pah[7] = (short)(u1.w & 0xffff); pal[7] = (short)(u1.w >> 16);
#pragma unroll
      for (int t = 0; t < 4; ++t) {
        int bo = SWZ(t * 16 + lr, kc * 64 + lk * 16);
        short8 vh = *reinterpret_cast<const short8*>(VhB + bo);
        short8 vl = *reinterpret_cast<const short8*>(VlB + bo);
        o[t] = __builtin_amdgcn_mfma_f32_16x16x32_bf16(pah, vh, o[t], 0, 0, 0);
        o[t] = __builtin_amdgcn_mfma_f32_16x16x32_bf16(pah, vl, o[t], 0, 0, 0);
        o[t] = __builtin_amdgcn_mfma_f32_16x16x32_bf16(pal, vh, o[t], 0, 0, 0);
      }
    }
  }
#undef ATTN_ISSUE

  if (!partial) {
    // ---- direct epilogue: normalize, store ctx as hi/lo bf16 planes ----
    float inv[4];
#pragma unroll
    for (int r = 0; r < 4; ++r) inv[r] = 1.f / l[r];
#pragma unroll
    for (int t = 0; t < 4; ++t)
#pragma unroll
      for (int r = 0; r < 4; ++r) {
        size_t idx = (size_t)(qb * 64 + w * 16 + lk * 4 + r) * D_MODEL +
                     h * H_DIM + t * 16 + lr;
        float v = o[t][r] * inv[r];
        ushort hh = f2bh(v);
        CTXh[idx] = hh;
        CTXl[idx] = f2bh(v - bh2f(hh));
      }
  } else {
    // ---- partial epilogue: unnormalized fp32 O + m + l ----
    const int slot = (h * 32 + (qb - 32)) * 2 + cidx;
    float* Ob = O_part + (size_t)slot * 4096;
#pragma unroll
    for (int t = 0; t < 4; ++t)
#pragma unroll
      for (int r = 0; r < 4; ++r)
        Ob[(w * 16 + lk * 4 + r) * 64 + t * 16 + lr] = o[t][r];
    if (lr == 0) {
#pragma unroll
      for (int r = 0; r < 4; ++r) {
        int row = w * 16 + lk * 4 + r;
        m_part[slot * 64 + row] = m[r];
        l_part[slot * 64 + row] = l[r];
      }
    }
  }
}

// ============================================================================
// Combine two partials per (h, qb>=32): O = sum O_c e^(m_c-M); ctx = O/L.
// Grid (32, 12), 256 threads; thread handles (row, 16 dims).
// ============================================================================
__global__ __launch_bounds__(256)
void attn_combine(const float* __restrict__ O_part,
                  const float* __restrict__ m_part,
                  const float* __restrict__ l_part,
                  ushort* __restrict__ CTXh, ushort* __restrict__ CTXl) {
  const int qb  = 32 + blockIdx.x;
  const int h   = blockIdx.y;
  const int tid = threadIdx.x;
  const int row = tid >> 2;        // 0..63
  const int d0  = (tid & 3) * 16;  // 0,16,32,48
  const int slot0 = (h * 32 + (qb - 32)) * 2;
  const int slot1 = slot0 + 1;

  float m0 = m_part[slot0 * 64 + row];
  float m1 = m_part[slot1 * 64 + row];
  float l0 = l_part[slot0 * 64 + row];
  float l1 = l_part[slot1 * 64 + row];
  float M  = fmaxf(m0, m1);
  float a0 = __expf(m0 - M);
  float a1 = __expf(m1 - M);
  float inv = 1.0f / (l0 * a0 + l1 * a1);

  const float* p0 = O_part + (size_t)slot0 * 4096 + row * 64 + d0;
  const float* p1 = O_part + (size_t)slot1 * 4096 + row * 64 + d0;
  size_t ob = (size_t)(qb * 64 + row) * D_MODEL + h * H_DIM + d0;
#pragma unroll
  for (int j = 0; j < 16; j += 4) {
    float4 x0 = *reinterpret_cast<const float4*>(p0 + j);
    float4 x1 = *reinterpret_cast<const float4*>(p1 + j);
    float4 v;
    v.x = (x0.x * a0 + x1.x * a1) * inv;
    v.y = (x0.y * a0 + x1.y * a1) * inv;
    v.z = (x0.z * a0 + x1.z * a1) * inv;
    v.w = (x0.w * a0 + x1.w * a1) * inv;
    ushort4 hv, lv;
    hv.x = f2bh(v.x); lv.x = f2bh(v.x - bh2f(hv.x));
    hv.y = f2bh(v.y); lv.y = f2bh(v.y - bh2f(hv.y));
    hv.z = f2bh(v.z); lv.z = f2bh(v.z - bh2f(hv.z));
    hv.w = f2bh(v.w); lv.w = f2bh(v.w - bh2f(hv.w));
    *reinterpret_cast<ushort4*>(&CTXh[ob + j]) = hv;
    *reinterpret_cast<ushort4*>(&CTXl[ob + j]) = lv;
  }
}

// ============================================================================
extern "C" void kernel_launch(void* const* d_in, const int* in_sizes, int n_in,
                              void* d_out, int out_size, void* d_ws,
                              size_t ws_size, hipStream_t stream) {
  // setup_inputs order: x, w_k, w_q, w_v, w_o, b_o
  const float* x  = (const float*)d_in[0];
  const float* wk = (const float*)d_in[1];
  const float* wq = (const float*)d_in[2];
  const float* wv = (const float*)d_in[3];
  const float* wo = (const float*)d_in[4];
  const float* bo = (const float*)d_in[5];
  float* out = (float*)d_out;

  // Workspace layout (ushort elements). CTX aliases Vr (dead after
  // convert_vt). Total ~85.3 MB (<= 88 MB proven in R2).
  ushort* xh   = (ushort*)d_ws;
  ushort* xl   = xh + NELEM;
  ushort* WH   = xl + NELEM;          // 4 planes: q,k,v,o
  ushort* WL   = WH + 4 * (size_t)WELEM;
  ushort* QKV  = WL + 4 * (size_t)WELEM;  // [Qh][Ql][Kh][Kl][Vrh][Vrl]
  ushort* Qh   = QKV;
  ushort* Ql   = Qh + NELEM;
  ushort* Kh   = Ql + NELEM;
  ushort* Kl   = Kh + NELEM;
  ushort* Vrh  = Kl + NELEM;
  ushort* Vrl  = Vrh + NELEM;
  ushort* Vth  = Vrl + NELEM;
  ushort* Vtl  = Vth + NELEM;
  ushort* CTXh = Vrh;  // alias: Vr dead after convert_vt
  ushort* CTXl = Vrl;
  float* O_part = (float*)(Vtl + NELEM);       // 768 slots x 64 x 64 fp32
  float* m_part = O_part + 768 * (size_t)4096; // 768 x 64
  float* l_part = m_part + 768 * 64;

  dim3 blk(256);
  convert_x<<<dim3(NELEM / 4 / 256), blk, 0, stream>>>(x, xh, xl);
  convert_w<<<dim3(WELEM / 4 / 256, 1, 4), blk, 0, stream>>>(wq, wk, wv, wo,
                                                             WH, WL);
  gemm_qkv_bf3<<<dim3(D_MODEL / 64, S_LEN / 128, 3), blk, 0, stream>>>(
      xh, xl, WH, WL, QKV);
  convert_vt<<<dim3(S_LEN / 64, N_HEAD), blk, 0, stream>>>(Vrh, Vrl, Vth, Vtl);
  attn_mfma<<<dim3(96, N_HEAD), blk, 0, stream>>>(
      Qh, Ql, Kh, Kl, Vth, Vtl, CTXh, CTXl, O_part, m_part, l_part);
  attn_combine<<<dim3(32, N_HEAD), blk, 0, stream>>>(O_part, m_part, l_part,
                                                     CTXh, CTXl);
  gemm_out_bf3<<<dim3(D_MODEL / 64, S_LEN / 128, 1), blk, 0, stream>>>(
      CTXh, CTXl, WH + 3 * (size_t)WELEM, WL + 3 * (size_t)WELEM, bo, out);
}